// Round 4
// baseline (286.154 us; speedup 1.0000x reference)
//
#include <hip/hip_runtime.h>

// BatchWiseSimCLR: out = mean_b,i logsumexp_{j!=i}(cos(z_bi,z_bj)/T) - mean_r cos(x_r,xp_r)/T
// 2B=128 batch rows, MS=512 items/batch, D=256, T=0.5.

#define TWO_B   128
#define MS      512
#define DDIM    256
#define NROWS   32768          // TWO_B * K = 128*256
#define TEMP_INV 2.0f
#define EPSN     1e-8f

typedef __attribute__((ext_vector_type(8))) short  short8;   // 8 x bf16 (4 VGPRs)
typedef __attribute__((ext_vector_type(4))) float  f32x4;    // MFMA acc

__device__ __forceinline__ unsigned short f2bf(float f) {
  union { float f; unsigned u; } c; c.f = f;
  unsigned r = (c.u + 0x7FFFu + ((c.u >> 16) & 1u)) >> 16;   // RNE
  return (unsigned short)r;
}

// ---------------- K1: row norms + positive loss ----------------
// one wave per row (4 rows / 256-thread block)
__global__ __launch_bounds__(256) void k_norm(
    const float* __restrict__ x, const float* __restrict__ xp,
    float* __restrict__ invx, float* __restrict__ invp, float* __restrict__ posacc) {
  const int wid = threadIdx.x >> 6, lane = threadIdx.x & 63;
  const int r = blockIdx.x * 4 + wid;
  const float4 a = ((const float4*)(x  + (size_t)r * DDIM))[lane];
  const float4 b = ((const float4*)(xp + (size_t)r * DDIM))[lane];
  float sxx = a.x*a.x + a.y*a.y + a.z*a.z + a.w*a.w;
  float spp = b.x*b.x + b.y*b.y + b.z*b.z + b.w*b.w;
  float sxp = a.x*b.x + a.y*b.y + a.z*b.z + a.w*b.w;
  #pragma unroll
  for (int m = 1; m < 64; m <<= 1) {
    sxx += __shfl_xor(sxx, m);
    spp += __shfl_xor(spp, m);
    sxp += __shfl_xor(sxp, m);
  }
  const float inx = 1.0f / fmaxf(sqrtf(sxx), EPSN);
  const float inp = 1.0f / fmaxf(sqrtf(spp), EPSN);
  if (lane == 0) { invx[r] = inx; invp[r] = inp; }
  __shared__ float cp[4];
  if (lane == 0) cp[wid] = sxp * inx * inp * TEMP_INV;
  __syncthreads();
  if (threadIdx.x == 0) atomicAdd(posacc, cp[0] + cp[1] + cp[2] + cp[3]);
}

// ---------------- K2: per-batch gram + exp row-sums ----------------
// stage a 64-row tile (bf16, XOR-swizzled) into LDS
__device__ __forceinline__ void stage_tile(
    unsigned short* dst, const float* __restrict__ x, const float* __restrict__ xp,
    const float* __restrict__ invx, const float* __restrict__ invp, int b, int tilebase) {
  const int t = threadIdx.x;
  const bool isp = (tilebase >= 256);                 // tiles never straddle x|x_pair
  const float* src = isp ? xp : x;
  const float* inv = isp ? invp : invx;
  const int base_i = isp ? (tilebase - 256) : tilebase;
  #pragma unroll
  for (int s = 0; s < 16; ++s) {
    const int u   = s * 256 + t;
    const int row = u >> 6, c4 = u & 63;              // 64 x float4 per row
    const int g   = (base_i + row) * TWO_B + b;       // source row in x / x_pair
    const float4 v = *(const float4*)(src + (size_t)g * DDIM + c4 * 4);
    const float sc = inv[g];
    ushort4 o;
    o.x = f2bf(v.x * sc); o.y = f2bf(v.y * sc);
    o.z = f2bf(v.z * sc); o.w = f2bf(v.w * sc);
    *(ushort4*)(dst + row * 256 + ((c4 * 4) ^ ((row & 7) << 3))) = o;  // swizzled
  }
}

// 4 waves; each wave owns 16 FULL rows (all 64 cols of the j-tile) so the
// per-wave row sums are complete before the log.
__global__ __launch_bounds__(256, 2) void k_neg(
    const float* __restrict__ x, const float* __restrict__ xp,
    const float* __restrict__ invx, const float* __restrict__ invp,
    float* __restrict__ negacc) {
  __shared__ __align__(16) unsigned short As[64 * 256];   // 32 KB
  __shared__ __align__(16) unsigned short Bs[64 * 256];   // 32 KB
  const int b  = blockIdx.x;          // b fastest -> same-b blocks share an XCD
  const int it = blockIdx.y;
  const int lane = threadIdx.x & 63, wid = threadIdx.x >> 6;

  stage_tile(As, x, xp, invx, invp, b, it * 64);

  float rowacc[4] = {0, 0, 0, 0};     // per-lane partial exp row-sums (r2 index)

  for (int jt = 0; jt < 8; ++jt) {
    __syncthreads();                                      // prior compute done
    stage_tile(Bs, x, xp, invx, invp, b, jt * 64);
    __syncthreads();

    f32x4 acc[4] = {{0,0,0,0},{0,0,0,0},{0,0,0,0},{0,0,0,0}};
    #pragma unroll
    for (int kk = 0; kk < 8; ++kk) {                      // D=256 / K=32
      const int col = kk * 32 + ((lane >> 4) << 3);       // ushort units
      const int ar  = wid * 16 + (lane & 15);
      const short8 av = *(const short8*)(As + ar * 256 + (col ^ ((ar & 7) << 3)));
      #pragma unroll
      for (int ni = 0; ni < 4; ++ni) {
        const int br = ni * 16 + (lane & 15);
        const short8 bv = *(const short8*)(Bs + br * 256 + (col ^ ((br & 7) << 3)));
        acc[ni] = __builtin_amdgcn_mfma_f32_16x16x32_bf16(av, bv, acc[ni], 0, 0, 0);
      }
    }

    // exp + diag-mask accumulate (sim <= 2, no max-shift needed)
    const int igb = it * 64 + wid * 16 + ((lane >> 4) << 2);
    #pragma unroll
    for (int ni = 0; ni < 4; ++ni) {
      const int jg = jt * 64 + ni * 16 + (lane & 15);
      #pragma unroll
      for (int r2 = 0; r2 < 4; ++r2) {
        const float s = acc[ni][r2] * TEMP_INV;
        rowacc[r2] += ((igb + r2) == jg) ? 0.0f : __expf(s);
      }
    }
  }

  // xor 1..8: full row sums within each 16-lane group (identical across the
  // group's 16 lanes). partial = sum of this group's 4 row-logs.
  float partial = 0.0f;
  #pragma unroll
  for (int r2 = 0; r2 < 4; ++r2) {
    float v = rowacc[r2];
    v += __shfl_xor(v, 1); v += __shfl_xor(v, 2);
    v += __shfl_xor(v, 4); v += __shfl_xor(v, 8);
    partial += __logf(v);
  }
  // butterfly across the 4 groups: lane l combines l^16, l^32, l^48 — one
  // REPRESENTATIVE per group -> every lane ends with exactly
  // p_g0+p_g1+p_g2+p_g3 (no 16x duplication; the R3 /16 was the bug).
  partial += __shfl_xor(partial, 16);
  partial += __shfl_xor(partial, 32);
  if (lane == 0) atomicAdd(negacc, partial);
}

// ---------------- K3: finalize ----------------
__global__ void k_fin(const float* __restrict__ ws, float* __restrict__ out) {
  out[0] = ws[1] * (1.0f / 65536.0f) - ws[0] * (1.0f / 32768.0f);
}

extern "C" void kernel_launch(void* const* d_in, const int* in_sizes, int n_in,
                              void* d_out, int out_size, void* d_ws, size_t ws_size,
                              hipStream_t stream) {
  const float* x  = (const float*)d_in[0];
  const float* xp = (const float*)d_in[1];
  float* wsf  = (float*)d_ws;
  float* pos  = wsf + 0;
  float* neg  = wsf + 1;
  float* invx = wsf + 8;
  float* invp = wsf + 8 + NROWS;
  float* out  = (float*)d_out;

  hipMemsetAsync(d_ws, 0, 8, stream);                       // zero the two accumulators
  k_norm<<<NROWS / 4, 256, 0, stream>>>(x, xp, invx, invp, pos);
  k_neg<<<dim3(TWO_B, 8), 256, 0, stream>>>(x, xp, invx, invp, neg);
  k_fin<<<1, 1, 0, stream>>>(wsf, out);
}

// Round 5
// 151.044 us; speedup vs baseline: 1.8945x; 1.8945x over previous
//
#include <hip/hip_runtime.h>

// BatchWiseSimCLR: out = mean_b,i logsumexp_{j!=i}(cos(z_bi,z_bj)/T) - mean_r cos(x_r,xp_r)/T
// 2B=128 batch rows, MS=512 items/batch, D=256, T=0.5.

#define TWO_B   128
#define MS      512
#define DDIM    256
#define NROWS   32768          // TWO_B * K = 128*256
#define TEMP_INV 2.0f
#define EPSN     1e-8f

typedef __attribute__((ext_vector_type(8))) short  short8;   // 8 x bf16 (4 VGPRs)
typedef __attribute__((ext_vector_type(4))) float  f32x4;    // MFMA acc

__device__ __forceinline__ unsigned short f2bf(float f) {
  union { float f; unsigned u; } c; c.f = f;
  unsigned r = (c.u + 0x7FFFu + ((c.u >> 16) & 1u)) >> 16;   // RNE
  return (unsigned short)r;
}

// ---------------- K1: row norms + positive loss ----------------
// 1024 blocks, one wave per row, 8 rows per wave (grid-stride).
// NO atomics: per-block partial -> posp[bid] (R4: 8192 same-address atomics
// serialized at ~13ns each = the whole 110us).
__global__ __launch_bounds__(256) void k_norm(
    const float* __restrict__ x, const float* __restrict__ xp,
    float* __restrict__ invx, float* __restrict__ invp, float* __restrict__ posp) {
  const int wid = threadIdx.x >> 6, lane = threadIdx.x & 63;
  float posl = 0.0f;
  #pragma unroll
  for (int itr = 0; itr < 8; ++itr) {
    const int r = itr * 4096 + blockIdx.x * 4 + wid;
    const float4 a = ((const float4*)(x  + (size_t)r * DDIM))[lane];
    const float4 b = ((const float4*)(xp + (size_t)r * DDIM))[lane];
    float sxx = a.x*a.x + a.y*a.y + a.z*a.z + a.w*a.w;
    float spp = b.x*b.x + b.y*b.y + b.z*b.z + b.w*b.w;
    float sxp = a.x*b.x + a.y*b.y + a.z*b.z + a.w*b.w;
    #pragma unroll
    for (int m = 1; m < 64; m <<= 1) {
      sxx += __shfl_xor(sxx, m);
      spp += __shfl_xor(spp, m);
      sxp += __shfl_xor(sxp, m);
    }
    const float inx = 1.0f / fmaxf(sqrtf(sxx), EPSN);
    const float inp = 1.0f / fmaxf(sqrtf(spp), EPSN);
    if (lane == 0) {
      invx[r] = inx; invp[r] = inp;
      posl += sxp * inx * inp * TEMP_INV;
    }
  }
  __shared__ float cp[4];
  if (lane == 0) cp[wid] = posl;
  __syncthreads();
  if (threadIdx.x == 0) posp[blockIdx.x] = cp[0] + cp[1] + cp[2] + cp[3];
}

// ---------------- K2: per-batch gram + exp row-sums ----------------
// stage a 64-row tile (bf16, XOR-swizzled) into LDS
__device__ __forceinline__ void stage_tile(
    unsigned short* dst, const float* __restrict__ x, const float* __restrict__ xp,
    const float* __restrict__ invx, const float* __restrict__ invp, int b, int tilebase) {
  const int t = threadIdx.x;
  const bool isp = (tilebase >= 256);                 // tiles never straddle x|x_pair
  const float* src = isp ? xp : x;
  const float* inv = isp ? invp : invx;
  const int base_i = isp ? (tilebase - 256) : tilebase;
  #pragma unroll
  for (int s = 0; s < 16; ++s) {
    const int u   = s * 256 + t;
    const int row = u >> 6, c4 = u & 63;              // 64 x float4 per row
    const int g   = (base_i + row) * TWO_B + b;       // source row in x / x_pair
    const float4 v = *(const float4*)(src + (size_t)g * DDIM + c4 * 4);
    const float sc = inv[g];
    ushort4 o;
    o.x = f2bf(v.x * sc); o.y = f2bf(v.y * sc);
    o.z = f2bf(v.z * sc); o.w = f2bf(v.w * sc);
    *(ushort4*)(dst + row * 256 + ((c4 * 4) ^ ((row & 7) << 3))) = o;  // swizzled
  }
}

// 4 waves; each wave owns 16 FULL rows (all 64 cols of the j-tile) so the
// per-wave row sums are complete before the log.
__global__ __launch_bounds__(256, 2) void k_neg(
    const float* __restrict__ x, const float* __restrict__ xp,
    const float* __restrict__ invx, const float* __restrict__ invp,
    float* __restrict__ negp) {
  __shared__ __align__(16) unsigned short As[64 * 256];   // 32 KB
  __shared__ __align__(16) unsigned short Bs[64 * 256];   // 32 KB
  const int b  = blockIdx.x;          // b fastest -> same-b blocks share an XCD
  const int it = blockIdx.y;
  const int lane = threadIdx.x & 63, wid = threadIdx.x >> 6;

  stage_tile(As, x, xp, invx, invp, b, it * 64);

  float rowacc[4] = {0, 0, 0, 0};     // per-lane partial exp row-sums (r2 index)

  for (int jt = 0; jt < 8; ++jt) {
    __syncthreads();                                      // prior compute done
    stage_tile(Bs, x, xp, invx, invp, b, jt * 64);
    __syncthreads();

    f32x4 acc[4] = {{0,0,0,0},{0,0,0,0},{0,0,0,0},{0,0,0,0}};
    #pragma unroll
    for (int kk = 0; kk < 8; ++kk) {                      // D=256 / K=32
      const int col = kk * 32 + ((lane >> 4) << 3);       // ushort units
      const int ar  = wid * 16 + (lane & 15);
      const short8 av = *(const short8*)(As + ar * 256 + (col ^ ((ar & 7) << 3)));
      #pragma unroll
      for (int ni = 0; ni < 4; ++ni) {
        const int br = ni * 16 + (lane & 15);
        const short8 bv = *(const short8*)(Bs + br * 256 + (col ^ ((br & 7) << 3)));
        acc[ni] = __builtin_amdgcn_mfma_f32_16x16x32_bf16(av, bv, acc[ni], 0, 0, 0);
      }
    }

    // exp + diag-mask accumulate (sim <= 2, no max-shift needed)
    const int igb = it * 64 + wid * 16 + ((lane >> 4) << 2);
    #pragma unroll
    for (int ni = 0; ni < 4; ++ni) {
      const int jg = jt * 64 + ni * 16 + (lane & 15);
      #pragma unroll
      for (int r2 = 0; r2 < 4; ++r2) {
        const float s = acc[ni][r2] * TEMP_INV;
        rowacc[r2] += ((igb + r2) == jg) ? 0.0f : __expf(s);
      }
    }
  }

  // xor 1..8: full row sums within each 16-lane group (identical across the
  // group's 16 lanes). partial = sum of this group's 4 row-logs.
  float partial = 0.0f;
  #pragma unroll
  for (int r2 = 0; r2 < 4; ++r2) {
    float v = rowacc[r2];
    v += __shfl_xor(v, 1); v += __shfl_xor(v, 2);
    v += __shfl_xor(v, 4); v += __shfl_xor(v, 8);
    partial += __logf(v);
  }
  // butterfly across the 4 groups: lane l combines l^16, l^32, l^48 — one
  // representative per group -> every lane holds p_g0+p_g1+p_g2+p_g3.
  partial += __shfl_xor(partial, 16);
  partial += __shfl_xor(partial, 32);

  // per-block combine via LDS -> ONE plain store (no atomics)
  __shared__ float sn[4];
  if (lane == 0) sn[wid] = partial;
  __syncthreads();
  if (threadIdx.x == 0)
    negp[blockIdx.y * TWO_B + blockIdx.x] = sn[0] + sn[1] + sn[2] + sn[3];
}

// ---------------- K3: finalize — reduce the two 1024-entry partial arrays ----------------
__global__ __launch_bounds__(256) void k_fin(
    const float* __restrict__ posp, const float* __restrict__ negp,
    float* __restrict__ out) {
  const int t = threadIdx.x, wid = t >> 6, lane = t & 63;
  const float4 p4 = ((const float4*)posp)[t];
  const float4 n4 = ((const float4*)negp)[t];
  float p = p4.x + p4.y + p4.z + p4.w;
  float n = n4.x + n4.y + n4.z + n4.w;
  #pragma unroll
  for (int m = 1; m < 64; m <<= 1) { p += __shfl_xor(p, m); n += __shfl_xor(n, m); }
  __shared__ float sp[4], sn[4];
  if (lane == 0) { sp[wid] = p; sn[wid] = n; }
  __syncthreads();
  if (t == 0) {
    const float pt = sp[0] + sp[1] + sp[2] + sp[3];
    const float nt = sn[0] + sn[1] + sn[2] + sn[3];
    out[0] = nt * (1.0f / 65536.0f) - pt * (1.0f / 32768.0f);
  }
}

extern "C" void kernel_launch(void* const* d_in, const int* in_sizes, int n_in,
                              void* d_out, int out_size, void* d_ws, size_t ws_size,
                              hipStream_t stream) {
  const float* x  = (const float*)d_in[0];
  const float* xp = (const float*)d_in[1];
  float* wsf  = (float*)d_ws;
  float* invx = wsf;                 // 32768
  float* invp = wsf + NROWS;         // 32768
  float* posp = wsf + 2 * NROWS;     // 1024
  float* negp = wsf + 2 * NROWS + 1024;  // 1024
  float* out  = (float*)d_out;

  k_norm<<<1024, 256, 0, stream>>>(x, xp, invx, invp, posp);
  k_neg<<<dim3(TWO_B, 8), 256, 0, stream>>>(x, xp, invx, invp, negp);
  k_fin<<<1, 256, 0, stream>>>(posp, negp, out);
}

// Round 6
// 130.594 us; speedup vs baseline: 2.1912x; 1.1566x over previous
//
#include <hip/hip_runtime.h>

// BatchWiseSimCLR: out = mean_b,i logsumexp_{j!=i}(cos(z_bi,z_bj)/T) - mean_r cos(x_r,xp_r)/T
// 2B=128 batch rows, MS=512 items/batch, D=256, T=0.5.

#define TWO_B   128
#define MS      512
#define DDIM    256
#define NROWS   32768          // TWO_B * K = 128*256
#define TEMP_INV 2.0f
#define EPSN     1e-8f

typedef __attribute__((ext_vector_type(8))) short  short8;   // 8 x bf16 (4 VGPRs)
typedef __attribute__((ext_vector_type(4))) float  f32x4;    // MFMA acc

__device__ __forceinline__ unsigned short f2bf(float f) {
  union { float f; unsigned u; } c; c.f = f;
  unsigned r = (c.u + 0x7FFFu + ((c.u >> 16) & 1u)) >> 16;   // RNE
  return (unsigned short)r;
}

// global_load_lds, 16B per lane; lds dest = wave-uniform base (+lane*16 by HW)
#define GLDS16(gp, lp)                                                         \
  __builtin_amdgcn_global_load_lds(                                            \
      (const __attribute__((address_space(1))) unsigned int*)(gp),             \
      (__attribute__((address_space(3))) unsigned int*)(lp), 16, 0, 0)

// ================= FAST PATH (needs 32MB+12KB workspace) =================

// ---- K1f: row norms + positive loss + write normalized bf16 zn ----
// zn layout: row (b*512 + j) of 256 ushorts, PRE-SWIZZLED within the row:
// ushort u stored at u ^ ((j&7)<<3)  (16B-granule XOR) so k_neg can
// global_load_lds linearly and ds_read with the swizzled offset.
// 2048 blocks x 4 waves, 4 rows/wave -> 8 waves/SIMD for latency hiding.
__global__ __launch_bounds__(256) void k_norm_f(
    const float* __restrict__ x, const float* __restrict__ xp,
    unsigned short* __restrict__ zn, float* __restrict__ posp) {
  const int wid = threadIdx.x >> 6, lane = threadIdx.x & 63;
  float posl = 0.0f;
  #pragma unroll
  for (int itr = 0; itr < 4; ++itr) {
    const int r = itr * 8192 + blockIdx.x * 4 + wid;
    const int b = r & 127, i = r >> 7;          // r = i*128 + b
    const float4 a = ((const float4*)(x  + (size_t)r * DDIM))[lane];
    const float4 p = ((const float4*)(xp + (size_t)r * DDIM))[lane];
    float sxx = a.x*a.x + a.y*a.y + a.z*a.z + a.w*a.w;
    float spp = p.x*p.x + p.y*p.y + p.z*p.z + p.w*p.w;
    float sxp = a.x*p.x + a.y*p.y + a.z*p.z + a.w*p.w;
    #pragma unroll
    for (int m = 1; m < 64; m <<= 1) {
      sxx += __shfl_xor(sxx, m);
      spp += __shfl_xor(spp, m);
      sxp += __shfl_xor(sxp, m);
    }
    const float inx = 1.0f / fmaxf(sqrtf(sxx), EPSN);
    const float inp = 1.0f / fmaxf(sqrtf(spp), EPSN);
    posl += sxp * inx * inp * TEMP_INV;         // same value in all lanes
    // swizzled in-row ushort offset (j&7 == i&7 for both j=i and j=256+i)
    const int us = (lane * 4) ^ ((i & 7) << 3);
    ushort4 ox, op;
    ox.x = f2bf(a.x * inx); ox.y = f2bf(a.y * inx);
    ox.z = f2bf(a.z * inx); ox.w = f2bf(a.w * inx);
    op.x = f2bf(p.x * inp); op.y = f2bf(p.y * inp);
    op.z = f2bf(p.z * inp); op.w = f2bf(p.w * inp);
    *(ushort4*)(zn + ((size_t)(b * MS + i)       * DDIM) + us) = ox;
    *(ushort4*)(zn + ((size_t)(b * MS + 256 + i) * DDIM) + us) = op;
  }
  __shared__ float cp[4];
  if (lane == 0) cp[wid] = posl;
  __syncthreads();
  if (threadIdx.x == 0) posp[blockIdx.x] = cp[0] + cp[1] + cp[2] + cp[3];
}

// ---- K2f: per-batch gram + exp row-sums; staging = pure global_load_lds ----
__global__ __launch_bounds__(256, 2) void k_neg_f(
    const unsigned short* __restrict__ zn, float* __restrict__ negp) {
  __shared__ __align__(16) unsigned short As[64 * 256];   // 32 KB
  __shared__ __align__(16) unsigned short Bs[64 * 256];   // 32 KB
  const int b  = blockIdx.x;          // b fastest -> same-b blocks share an XCD
  const int it = blockIdx.y;
  const int lane = threadIdx.x & 63, wid = threadIdx.x >> 6;

  // stage A tile (contiguous 32 KB): 8 x 1KB chunks per wave
  {
    const unsigned short* g = zn + (size_t)(b * MS + it * 64) * DDIM;
    #pragma unroll
    for (int s = 0; s < 8; ++s) {
      const int c = wid * 8 + s;                // chunk = 512 ushorts = 1 KB
      GLDS16(g + c * 512 + lane * 8, As + c * 512);
    }
  }

  float rowacc[4] = {0, 0, 0, 0};     // per-lane partial exp row-sums (r2 index)

  for (int jt = 0; jt < 8; ++jt) {
    __syncthreads();                  // prior compute done; pending DMA drained
    if (jt != it) {
      const unsigned short* g = zn + (size_t)(b * MS + jt * 64) * DDIM;
      #pragma unroll
      for (int s = 0; s < 8; ++s) {
        const int c = wid * 8 + s;
        GLDS16(g + c * 512 + lane * 8, Bs + c * 512);
      }
    }
    __syncthreads();                  // B tile ready (or we reuse As)
    const unsigned short* Bsrc = (jt == it) ? As : Bs;

    f32x4 acc[4] = {{0,0,0,0},{0,0,0,0},{0,0,0,0},{0,0,0,0}};
    #pragma unroll
    for (int kk = 0; kk < 8; ++kk) {                      // D=256 / K=32
      const int col = kk * 32 + ((lane >> 4) << 3);       // ushort units
      const int ar  = wid * 16 + (lane & 15);
      const short8 av = *(const short8*)(As + ar * 256 + (col ^ ((ar & 7) << 3)));
      #pragma unroll
      for (int ni = 0; ni < 4; ++ni) {
        const int br = ni * 16 + (lane & 15);
        const short8 bv = *(const short8*)(Bsrc + br * 256 + (col ^ ((br & 7) << 3)));
        acc[ni] = __builtin_amdgcn_mfma_f32_16x16x32_bf16(av, bv, acc[ni], 0, 0, 0);
      }
    }

    // exp + diag-mask accumulate (sim <= 2, no max-shift needed)
    const int igb = it * 64 + wid * 16 + ((lane >> 4) << 2);
    #pragma unroll
    for (int ni = 0; ni < 4; ++ni) {
      const int jg = jt * 64 + ni * 16 + (lane & 15);
      #pragma unroll
      for (int r2 = 0; r2 < 4; ++r2) {
        const float s = acc[ni][r2] * TEMP_INV;
        rowacc[r2] += ((igb + r2) == jg) ? 0.0f : __expf(s);
      }
    }
  }

  // xor 1..8: full row sums within each 16-lane group; then one log per row
  float partial = 0.0f;
  #pragma unroll
  for (int r2 = 0; r2 < 4; ++r2) {
    float v = rowacc[r2];
    v += __shfl_xor(v, 1); v += __shfl_xor(v, 2);
    v += __shfl_xor(v, 4); v += __shfl_xor(v, 8);
    partial += __logf(v);
  }
  // butterfly across the 4 groups: every lane ends with p_g0+p_g1+p_g2+p_g3
  partial += __shfl_xor(partial, 16);
  partial += __shfl_xor(partial, 32);

  __shared__ float sn[4];
  if (lane == 0) sn[wid] = partial;
  __syncthreads();
  if (threadIdx.x == 0)
    negp[blockIdx.y * TWO_B + blockIdx.x] = sn[0] + sn[1] + sn[2] + sn[3];
}

// ---- K3f: finalize — posp has 2048 entries, negp 1024 ----
__global__ __launch_bounds__(256) void k_fin_f(
    const float* __restrict__ posp, const float* __restrict__ negp,
    float* __restrict__ out) {
  const int t = threadIdx.x, wid = t >> 6, lane = t & 63;
  const float4 p4a = ((const float4*)posp)[t * 2];
  const float4 p4b = ((const float4*)posp)[t * 2 + 1];
  const float4 n4  = ((const float4*)negp)[t];
  float p = p4a.x + p4a.y + p4a.z + p4a.w + p4b.x + p4b.y + p4b.z + p4b.w;
  float n = n4.x + n4.y + n4.z + n4.w;
  #pragma unroll
  for (int m = 1; m < 64; m <<= 1) { p += __shfl_xor(p, m); n += __shfl_xor(n, m); }
  __shared__ float sp[4], sq[4];
  if (lane == 0) { sp[wid] = p; sq[wid] = n; }
  __syncthreads();
  if (t == 0) {
    const float pt = sp[0] + sp[1] + sp[2] + sp[3];
    const float nt = sq[0] + sq[1] + sq[2] + sq[3];
    out[0] = nt * (1.0f / 65536.0f) - pt * (1.0f / 32768.0f);
  }
}

// ================= FALLBACK PATH (R5, small workspace) =================

__global__ __launch_bounds__(256) void k_norm(
    const float* __restrict__ x, const float* __restrict__ xp,
    float* __restrict__ invx, float* __restrict__ invp, float* __restrict__ posp) {
  const int wid = threadIdx.x >> 6, lane = threadIdx.x & 63;
  float posl = 0.0f;
  #pragma unroll
  for (int itr = 0; itr < 8; ++itr) {
    const int r = itr * 4096 + blockIdx.x * 4 + wid;
    const float4 a = ((const float4*)(x  + (size_t)r * DDIM))[lane];
    const float4 b = ((const float4*)(xp + (size_t)r * DDIM))[lane];
    float sxx = a.x*a.x + a.y*a.y + a.z*a.z + a.w*a.w;
    float spp = b.x*b.x + b.y*b.y + b.z*b.z + b.w*b.w;
    float sxp = a.x*b.x + a.y*b.y + a.z*b.z + a.w*b.w;
    #pragma unroll
    for (int m = 1; m < 64; m <<= 1) {
      sxx += __shfl_xor(sxx, m);
      spp += __shfl_xor(spp, m);
      sxp += __shfl_xor(sxp, m);
    }
    const float inx = 1.0f / fmaxf(sqrtf(sxx), EPSN);
    const float inp = 1.0f / fmaxf(sqrtf(spp), EPSN);
    if (lane == 0) {
      invx[r] = inx; invp[r] = inp;
      posl += sxp * inx * inp * TEMP_INV;
    }
  }
  __shared__ float cp[4];
  if (lane == 0) cp[wid] = posl;
  __syncthreads();
  if (threadIdx.x == 0) posp[blockIdx.x] = cp[0] + cp[1] + cp[2] + cp[3];
}

__device__ __forceinline__ void stage_tile(
    unsigned short* dst, const float* __restrict__ x, const float* __restrict__ xp,
    const float* __restrict__ invx, const float* __restrict__ invp, int b, int tilebase) {
  const int t = threadIdx.x;
  const bool isp = (tilebase >= 256);
  const float* src = isp ? xp : x;
  const float* inv = isp ? invp : invx;
  const int base_i = isp ? (tilebase - 256) : tilebase;
  #pragma unroll
  for (int s = 0; s < 16; ++s) {
    const int u   = s * 256 + t;
    const int row = u >> 6, c4 = u & 63;
    const int g   = (base_i + row) * TWO_B + b;
    const float4 v = *(const float4*)(src + (size_t)g * DDIM + c4 * 4);
    const float sc = inv[g];
    ushort4 o;
    o.x = f2bf(v.x * sc); o.y = f2bf(v.y * sc);
    o.z = f2bf(v.z * sc); o.w = f2bf(v.w * sc);
    *(ushort4*)(dst + row * 256 + ((c4 * 4) ^ ((row & 7) << 3))) = o;
  }
}

__global__ __launch_bounds__(256, 2) void k_neg(
    const float* __restrict__ x, const float* __restrict__ xp,
    const float* __restrict__ invx, const float* __restrict__ invp,
    float* __restrict__ negp) {
  __shared__ __align__(16) unsigned short As[64 * 256];
  __shared__ __align__(16) unsigned short Bs[64 * 256];
  const int b  = blockIdx.x;
  const int it = blockIdx.y;
  const int lane = threadIdx.x & 63, wid = threadIdx.x >> 6;

  stage_tile(As, x, xp, invx, invp, b, it * 64);
  float rowacc[4] = {0, 0, 0, 0};

  for (int jt = 0; jt < 8; ++jt) {
    __syncthreads();
    stage_tile(Bs, x, xp, invx, invp, b, jt * 64);
    __syncthreads();

    f32x4 acc[4] = {{0,0,0,0},{0,0,0,0},{0,0,0,0},{0,0,0,0}};
    #pragma unroll
    for (int kk = 0; kk < 8; ++kk) {
      const int col = kk * 32 + ((lane >> 4) << 3);
      const int ar  = wid * 16 + (lane & 15);
      const short8 av = *(const short8*)(As + ar * 256 + (col ^ ((ar & 7) << 3)));
      #pragma unroll
      for (int ni = 0; ni < 4; ++ni) {
        const int br = ni * 16 + (lane & 15);
        const short8 bv = *(const short8*)(Bs + br * 256 + (col ^ ((br & 7) << 3)));
        acc[ni] = __builtin_amdgcn_mfma_f32_16x16x32_bf16(av, bv, acc[ni], 0, 0, 0);
      }
    }
    const int igb = it * 64 + wid * 16 + ((lane >> 4) << 2);
    #pragma unroll
    for (int ni = 0; ni < 4; ++ni) {
      const int jg = jt * 64 + ni * 16 + (lane & 15);
      #pragma unroll
      for (int r2 = 0; r2 < 4; ++r2) {
        const float s = acc[ni][r2] * TEMP_INV;
        rowacc[r2] += ((igb + r2) == jg) ? 0.0f : __expf(s);
      }
    }
  }

  float partial = 0.0f;
  #pragma unroll
  for (int r2 = 0; r2 < 4; ++r2) {
    float v = rowacc[r2];
    v += __shfl_xor(v, 1); v += __shfl_xor(v, 2);
    v += __shfl_xor(v, 4); v += __shfl_xor(v, 8);
    partial += __logf(v);
  }
  partial += __shfl_xor(partial, 16);
  partial += __shfl_xor(partial, 32);

  __shared__ float sn[4];
  if (lane == 0) sn[wid] = partial;
  __syncthreads();
  if (threadIdx.x == 0)
    negp[blockIdx.y * TWO_B + blockIdx.x] = sn[0] + sn[1] + sn[2] + sn[3];
}

__global__ __launch_bounds__(256) void k_fin(
    const float* __restrict__ posp, const float* __restrict__ negp,
    float* __restrict__ out) {
  const int t = threadIdx.x, wid = t >> 6, lane = t & 63;
  const float4 p4 = ((const float4*)posp)[t];
  const float4 n4 = ((const float4*)negp)[t];
  float p = p4.x + p4.y + p4.z + p4.w;
  float n = n4.x + n4.y + n4.z + n4.w;
  #pragma unroll
  for (int m = 1; m < 64; m <<= 1) { p += __shfl_xor(p, m); n += __shfl_xor(n, m); }
  __shared__ float sp[4], sq[4];
  if (lane == 0) { sp[wid] = p; sq[wid] = n; }
  __syncthreads();
  if (t == 0) {
    const float pt = sp[0] + sp[1] + sp[2] + sp[3];
    const float nt = sq[0] + sq[1] + sq[2] + sq[3];
    out[0] = nt * (1.0f / 65536.0f) - pt * (1.0f / 32768.0f);
  }
}

extern "C" void kernel_launch(void* const* d_in, const int* in_sizes, int n_in,
                              void* d_out, int out_size, void* d_ws, size_t ws_size,
                              hipStream_t stream) {
  const float* x  = (const float*)d_in[0];
  const float* xp = (const float*)d_in[1];
  float* wsf = (float*)d_ws;
  float* out = (float*)d_out;

  const size_t need_fast = (size_t)3072 * 4 + (size_t)NROWS * MS / TWO_B * 0  // (readability)
                         + (size_t)65536 * DDIM * 2;  // zn: 65536 rows x 256 ushorts = 32 MB
  if (ws_size >= need_fast + 12288) {
    float* posp = wsf;                       // 2048
    float* negp = wsf + 2048;                // 1024
    unsigned short* zn = (unsigned short*)(wsf + 3072);
    k_norm_f<<<2048, 256, 0, stream>>>(x, xp, zn, posp);
    k_neg_f<<<dim3(TWO_B, 8), 256, 0, stream>>>(zn, negp);
    k_fin_f<<<1, 256, 0, stream>>>(posp, negp, out);
  } else {
    float* invx = wsf;
    float* invp = wsf + NROWS;
    float* posp = wsf + 2 * NROWS;
    float* negp = wsf + 2 * NROWS + 1024;
    k_norm<<<1024, 256, 0, stream>>>(x, xp, invx, invp, posp);
    k_neg<<<dim3(TWO_B, 8), 256, 0, stream>>>(x, xp, invx, invp, negp);
    k_fin<<<1, 256, 0, stream>>>(posp, negp, out);
  }
}

// Round 7
// 121.308 us; speedup vs baseline: 2.3589x; 1.0765x over previous
//
#include <hip/hip_runtime.h>

// BatchWiseSimCLR: out = mean_b,i logsumexp_{j!=i}(cos(z_bi,z_bj)/T) - mean_r cos(x_r,xp_r)/T
// 2B=128 batch rows, MS=512 items/batch, D=256, T=0.5.

#define TWO_B   128
#define MS      512
#define DDIM    256
#define NROWS   32768          // TWO_B * K = 128*256
#define TEMP_INV 2.0f
#define EPSN     1e-8f
#define SQRT2   1.41421356237f

typedef __attribute__((ext_vector_type(8))) short  short8;   // 8 x bf16 (4 VGPRs)
typedef __attribute__((ext_vector_type(4))) float  f32x4;    // MFMA acc

__device__ __forceinline__ unsigned short f2bf(float f) {
  union { float f; unsigned u; } c; c.f = f;
  unsigned r = (c.u + 0x7FFFu + ((c.u >> 16) & 1u)) >> 16;   // RNE
  return (unsigned short)r;
}

// global_load_lds, 16B per lane; lds dest = wave-uniform base (+lane*16 by HW)
#define GLDS16(gp, lp)                                                         \
  __builtin_amdgcn_global_load_lds(                                            \
      (const __attribute__((address_space(1))) unsigned int*)(gp),             \
      (__attribute__((address_space(3))) unsigned int*)(lp), 16, 0, 0)

// ================= FAST PATH (needs 32MB+4KB workspace) =================

// ---- K1f: row norms + write normalized bf16 zn (scaled by sqrt2) ----
// zn row (b*512+j): 256 ushorts, pre-swizzled in 16B granules:
// ushort u at offset u ^ ((j&7)<<3). sqrt2 fold: dot(zn_i,zn_j) = 2*cos = cos/T.
__global__ __launch_bounds__(256) void k_norm_f(
    const float* __restrict__ x, const float* __restrict__ xp,
    unsigned short* __restrict__ zn) {
  const int wid = threadIdx.x >> 6, lane = threadIdx.x & 63;
  #pragma unroll
  for (int itr = 0; itr < 4; ++itr) {
    const int r = itr * 8192 + blockIdx.x * 4 + wid;
    const int b = r & 127, i = r >> 7;          // r = i*128 + b
    const float4 a = ((const float4*)(x  + (size_t)r * DDIM))[lane];
    const float4 p = ((const float4*)(xp + (size_t)r * DDIM))[lane];
    float sxx = a.x*a.x + a.y*a.y + a.z*a.z + a.w*a.w;
    float spp = p.x*p.x + p.y*p.y + p.z*p.z + p.w*p.w;
    #pragma unroll
    for (int m = 1; m < 64; m <<= 1) {
      sxx += __shfl_xor(sxx, m);
      spp += __shfl_xor(spp, m);
    }
    const float inx = SQRT2 / fmaxf(sqrtf(sxx), EPSN);
    const float inp = SQRT2 / fmaxf(sqrtf(spp), EPSN);
    const int us = (lane * 4) ^ ((i & 7) << 3);
    ushort4 ox, op;
    ox.x = f2bf(a.x * inx); ox.y = f2bf(a.y * inx);
    ox.z = f2bf(a.z * inx); ox.w = f2bf(a.w * inx);
    op.x = f2bf(p.x * inp); op.y = f2bf(p.y * inp);
    op.z = f2bf(p.z * inp); op.w = f2bf(p.w * inp);
    *(ushort4*)(zn + ((size_t)(b * MS + i)       * DDIM) + us) = ox;
    *(ushort4*)(zn + ((size_t)(b * MS + 256 + i) * DDIM) + us) = op;
  }
}

// ---- K2f: gram + exp row-sums. A-frags in regs (wave owns 32 rows),
// B double-buffered via global_load_lds + counted vmcnt (m201 pattern).
__device__ __forceinline__ void stage_b(const unsigned short* g,
                                        unsigned short* d, int wid, int lane) {
  #pragma unroll
  for (int s = 0; s < 8; ++s) {
    const int c = wid * 8 + s;                  // 1 KB chunks
    GLDS16(g + c * 512 + lane * 8, d + c * 512);
  }
}

__global__ __launch_bounds__(256) void k_neg_f(
    const unsigned short* __restrict__ zn,
    float* __restrict__ negp, float* __restrict__ posn) {
  __shared__ __align__(16) unsigned short buf[2][64 * 256];   // 2 x 32 KB
  const int b  = blockIdx.x;      // linear id = it*128+b; 128%8==0 -> same-b same-XCD
  const int it = blockIdx.y;      // 0..3, 128-row A tile
  const int lane = threadIdx.x & 63, wid = threadIdx.x >> 6;

  // stage A (128 rows) into buf0 (rows 0-63) + buf1 (rows 64-127)
  {
    const unsigned short* gA = zn + (size_t)(b * MS + it * 128) * DDIM;
    #pragma unroll
    for (int s = 0; s < 8; ++s) {
      const int c = wid * 8 + s;
      GLDS16(gA + c * 512 + lane * 8, buf[0] + c * 512);
      GLDS16(gA + 32768 + c * 512 + lane * 8, buf[1] + c * 512);
    }
  }
  __syncthreads();

  // A-frags -> regs: wave owns A-rows wid*32..wid*32+31
  short8 av[2][8];
  {
    const unsigned short* src = buf[wid >> 1];
    #pragma unroll
    for (int rb = 0; rb < 2; ++rb) {
      const int ar = (wid & 1) * 32 + rb * 16 + (lane & 15);  // local row in buffer
      #pragma unroll
      for (int kk = 0; kk < 8; ++kk) {
        const int col = kk * 32 + ((lane >> 4) << 3);
        av[rb][kk] = *(const short8*)(src + ar * 256 + (col ^ ((ar & 7) << 3)));
      }
    }
  }
  __syncthreads();                              // all A reads done; bufs free

  // B pipeline: tile jt lives in buf[jt&1]; keep 2 tiles in flight
  const unsigned short* gB = zn + (size_t)b * MS * DDIM;
  stage_b(gB, buf[0], wid, lane);               // tile 0
  stage_b(gB + 32768, buf[1], wid, lane);       // tile 1

  float rowacc[2][4] = {{0,0,0,0},{0,0,0,0}};
  float posl = 0.0f;

  #pragma unroll
  for (int jt = 0; jt < 8; ++jt) {
    // wait: own chunks of tile jt done (8 newest = tile jt+1 may stay in flight)
    if (jt == 7) asm volatile("s_waitcnt vmcnt(0)" ::: "memory");
    else         asm volatile("s_waitcnt vmcnt(8)" ::: "memory");
    __builtin_amdgcn_sched_barrier(0);
    __builtin_amdgcn_s_barrier();               // tile jt fully in LDS
    __builtin_amdgcn_sched_barrier(0);

    const unsigned short* Bsrc = buf[jt & 1];
    f32x4 acc[2][4] = {{{0,0,0,0},{0,0,0,0},{0,0,0,0},{0,0,0,0}},
                       {{0,0,0,0},{0,0,0,0},{0,0,0,0},{0,0,0,0}}};
    #pragma unroll
    for (int kk = 0; kk < 8; ++kk) {
      const int col = kk * 32 + ((lane >> 4) << 3);
      #pragma unroll
      for (int ni = 0; ni < 4; ++ni) {
        const int br = ni * 16 + (lane & 15);
        const short8 bv = *(const short8*)(Bsrc + br * 256 + (col ^ ((br & 7) << 3)));
        acc[0][ni] = __builtin_amdgcn_mfma_f32_16x16x32_bf16(av[0][kk], bv, acc[0][ni], 0, 0, 0);
        acc[1][ni] = __builtin_amdgcn_mfma_f32_16x16x32_bf16(av[1][kk], bv, acc[1][ni], 0, 0, 0);
      }
    }

    // epilogue: s = acc = 2*cos = cos/T. diag mask + exp; pos at jg==ig+256.
    #pragma unroll
    for (int rb = 0; rb < 2; ++rb) {
      const int igb = it * 128 + wid * 32 + rb * 16 + ((lane >> 4) << 2);
      #pragma unroll
      for (int ni = 0; ni < 4; ++ni) {
        const int jg = jt * 64 + ni * 16 + (lane & 15);
        #pragma unroll
        for (int r2 = 0; r2 < 4; ++r2) {
          const int ig = igb + r2;
          const float s = acc[rb][ni][r2];
          rowacc[rb][r2] += (ig == jg) ? 0.0f : __expf(s);
          posl += (ig + 256 == jg) ? s : 0.0f;
        }
      }
    }
    __builtin_amdgcn_sched_barrier(0);
    __builtin_amdgcn_s_barrier();               // compute-jt done; buf[jt&1] free
    __builtin_amdgcn_sched_barrier(0);
    if (jt < 6) stage_b(gB + (size_t)(jt + 2) * 32768, buf[jt & 1], wid, lane);
  }

  // full row sums within each 16-lane group, then log
  float partial = 0.0f;
  #pragma unroll
  for (int rb = 0; rb < 2; ++rb)
    #pragma unroll
    for (int r2 = 0; r2 < 4; ++r2) {
      float v = rowacc[rb][r2];
      v += __shfl_xor(v, 1); v += __shfl_xor(v, 2);
      v += __shfl_xor(v, 4); v += __shfl_xor(v, 8);
      partial += __logf(v);
    }
  // one representative per 16-lane group -> wave total in every lane
  partial += __shfl_xor(partial, 16);
  partial += __shfl_xor(partial, 32);
  // posl: distinct contributions per lane -> full butterfly
  #pragma unroll
  for (int m = 1; m < 64; m <<= 1) posl += __shfl_xor(posl, m);

  __shared__ float sn[4], sp2[4];
  if (lane == 0) { sn[wid] = partial; sp2[wid] = posl; }
  __syncthreads();
  if (threadIdx.x == 0) {
    const int bid = blockIdx.y * TWO_B + blockIdx.x;
    negp[bid] = sn[0] + sn[1] + sn[2] + sn[3];
    posn[bid] = sp2[0] + sp2[1] + sp2[2] + sp2[3];
  }
}

// ---- K3f: reduce the two 512-entry partial arrays ----
__global__ __launch_bounds__(256) void k_fin_f(
    const float* __restrict__ posn, const float* __restrict__ negp,
    float* __restrict__ out) {
  const int t = threadIdx.x, wid = t >> 6, lane = t & 63;
  float p = posn[t] + posn[t + 256];
  float n = negp[t] + negp[t + 256];
  #pragma unroll
  for (int m = 1; m < 64; m <<= 1) { p += __shfl_xor(p, m); n += __shfl_xor(n, m); }
  __shared__ float sp[4], sq[4];
  if (lane == 0) { sp[wid] = p; sq[wid] = n; }
  __syncthreads();
  if (t == 0) {
    const float pt = sp[0] + sp[1] + sp[2] + sp[3];
    const float nt = sq[0] + sq[1] + sq[2] + sq[3];
    out[0] = nt * (1.0f / 65536.0f) - pt * (1.0f / 32768.0f);
  }
}

// ================= FALLBACK PATH (R5, small workspace, verified) =================

__global__ __launch_bounds__(256) void k_norm(
    const float* __restrict__ x, const float* __restrict__ xp,
    float* __restrict__ invx, float* __restrict__ invp, float* __restrict__ posp) {
  const int wid = threadIdx.x >> 6, lane = threadIdx.x & 63;
  float posl = 0.0f;
  #pragma unroll
  for (int itr = 0; itr < 8; ++itr) {
    const int r = itr * 4096 + blockIdx.x * 4 + wid;
    const float4 a = ((const float4*)(x  + (size_t)r * DDIM))[lane];
    const float4 b = ((const float4*)(xp + (size_t)r * DDIM))[lane];
    float sxx = a.x*a.x + a.y*a.y + a.z*a.z + a.w*a.w;
    float spp = b.x*b.x + b.y*b.y + b.z*b.z + b.w*b.w;
    float sxp = a.x*b.x + a.y*b.y + a.z*b.z + a.w*b.w;
    #pragma unroll
    for (int m = 1; m < 64; m <<= 1) {
      sxx += __shfl_xor(sxx, m);
      spp += __shfl_xor(spp, m);
      sxp += __shfl_xor(sxp, m);
    }
    const float inx = 1.0f / fmaxf(sqrtf(sxx), EPSN);
    const float inp = 1.0f / fmaxf(sqrtf(spp), EPSN);
    if (lane == 0) {
      invx[r] = inx; invp[r] = inp;
      posl += sxp * inx * inp * TEMP_INV;
    }
  }
  __shared__ float cp[4];
  if (lane == 0) cp[wid] = posl;
  __syncthreads();
  if (threadIdx.x == 0) posp[blockIdx.x] = cp[0] + cp[1] + cp[2] + cp[3];
}

__device__ __forceinline__ void stage_tile(
    unsigned short* dst, const float* __restrict__ x, const float* __restrict__ xp,
    const float* __restrict__ invx, const float* __restrict__ invp, int b, int tilebase) {
  const int t = threadIdx.x;
  const bool isp = (tilebase >= 256);
  const float* src = isp ? xp : x;
  const float* inv = isp ? invp : invx;
  const int base_i = isp ? (tilebase - 256) : tilebase;
  #pragma unroll
  for (int s = 0; s < 16; ++s) {
    const int u   = s * 256 + t;
    const int row = u >> 6, c4 = u & 63;
    const int g   = (base_i + row) * TWO_B + b;
    const float4 v = *(const float4*)(src + (size_t)g * DDIM + c4 * 4);
    const float sc = inv[g];
    ushort4 o;
    o.x = f2bf(v.x * sc); o.y = f2bf(v.y * sc);
    o.z = f2bf(v.z * sc); o.w = f2bf(v.w * sc);
    *(ushort4*)(dst + row * 256 + ((c4 * 4) ^ ((row & 7) << 3))) = o;
  }
}

__global__ __launch_bounds__(256, 2) void k_neg(
    const float* __restrict__ x, const float* __restrict__ xp,
    const float* __restrict__ invx, const float* __restrict__ invp,
    float* __restrict__ negp) {
  __shared__ __align__(16) unsigned short As[64 * 256];
  __shared__ __align__(16) unsigned short Bs[64 * 256];
  const int b  = blockIdx.x;
  const int it = blockIdx.y;
  const int lane = threadIdx.x & 63, wid = threadIdx.x >> 6;

  stage_tile(As, x, xp, invx, invp, b, it * 64);
  float rowacc[4] = {0, 0, 0, 0};

  for (int jt = 0; jt < 8; ++jt) {
    __syncthreads();
    stage_tile(Bs, x, xp, invx, invp, b, jt * 64);
    __syncthreads();

    f32x4 acc[4] = {{0,0,0,0},{0,0,0,0},{0,0,0,0},{0,0,0,0}};
    #pragma unroll
    for (int kk = 0; kk < 8; ++kk) {
      const int col = kk * 32 + ((lane >> 4) << 3);
      const int ar  = wid * 16 + (lane & 15);
      const short8 av = *(const short8*)(As + ar * 256 + (col ^ ((ar & 7) << 3)));
      #pragma unroll
      for (int ni = 0; ni < 4; ++ni) {
        const int br = ni * 16 + (lane & 15);
        const short8 bv = *(const short8*)(Bs + br * 256 + (col ^ ((br & 7) << 3)));
        acc[ni] = __builtin_amdgcn_mfma_f32_16x16x32_bf16(av, bv, acc[ni], 0, 0, 0);
      }
    }
    const int igb = it * 64 + wid * 16 + ((lane >> 4) << 2);
    #pragma unroll
    for (int ni = 0; ni < 4; ++ni) {
      const int jg = jt * 64 + ni * 16 + (lane & 15);
      #pragma unroll
      for (int r2 = 0; r2 < 4; ++r2) {
        const float s = acc[ni][r2] * TEMP_INV;
        rowacc[r2] += ((igb + r2) == jg) ? 0.0f : __expf(s);
      }
    }
  }

  float partial = 0.0f;
  #pragma unroll
  for (int r2 = 0; r2 < 4; ++r2) {
    float v = rowacc[r2];
    v += __shfl_xor(v, 1); v += __shfl_xor(v, 2);
    v += __shfl_xor(v, 4); v += __shfl_xor(v, 8);
    partial += __logf(v);
  }
  partial += __shfl_xor(partial, 16);
  partial += __shfl_xor(partial, 32);

  __shared__ float sn[4];
  if (lane == 0) sn[wid] = partial;
  __syncthreads();
  if (threadIdx.x == 0)
    negp[blockIdx.y * TWO_B + blockIdx.x] = sn[0] + sn[1] + sn[2] + sn[3];
}

__global__ __launch_bounds__(256) void k_fin(
    const float* __restrict__ posp, const float* __restrict__ negp,
    float* __restrict__ out) {
  const int t = threadIdx.x, wid = t >> 6, lane = t & 63;
  const float4 p4 = ((const float4*)posp)[t];
  const float4 n4 = ((const float4*)negp)[t];
  float p = p4.x + p4.y + p4.z + p4.w;
  float n = n4.x + n4.y + n4.z + n4.w;
  #pragma unroll
  for (int m = 1; m < 64; m <<= 1) { p += __shfl_xor(p, m); n += __shfl_xor(n, m); }
  __shared__ float sp[4], sq[4];
  if (lane == 0) { sp[wid] = p; sq[wid] = n; }
  __syncthreads();
  if (t == 0) {
    const float pt = sp[0] + sp[1] + sp[2] + sp[3];
    const float nt = sq[0] + sq[1] + sq[2] + sq[3];
    out[0] = nt * (1.0f / 65536.0f) - pt * (1.0f / 32768.0f);
  }
}

extern "C" void kernel_launch(void* const* d_in, const int* in_sizes, int n_in,
                              void* d_out, int out_size, void* d_ws, size_t ws_size,
                              hipStream_t stream) {
  const float* x  = (const float*)d_in[0];
  const float* xp = (const float*)d_in[1];
  float* wsf = (float*)d_ws;
  float* out = (float*)d_out;

  const size_t need_fast = 4096 + (size_t)65536 * DDIM * 2;   // partials + 32MB zn
  if (ws_size >= need_fast) {
    float* negp = wsf;                        // 512
    float* posn = wsf + 512;                  // 512
    unsigned short* zn = (unsigned short*)(wsf + 1024);
    k_norm_f<<<2048, 256, 0, stream>>>(x, xp, zn);
    k_neg_f<<<dim3(TWO_B, 4), 256, 0, stream>>>(zn, negp, posn);
    k_fin_f<<<1, 256, 0, stream>>>(posn, negp, out);
  } else {
    float* invx = wsf;
    float* invp = wsf + NROWS;
    float* posp = wsf + 2 * NROWS;
    float* negp = wsf + 2 * NROWS + 1024;
    k_norm<<<1024, 256, 0, stream>>>(x, xp, invx, invp, posp);
    k_neg<<<dim3(TWO_B, 8), 256, 0, stream>>>(x, xp, invx, invp, negp);
    k_fin<<<1, 256, 0, stream>>>(posp, negp, out);
  }
}

// Round 8
// 119.051 us; speedup vs baseline: 2.4036x; 1.0190x over previous
//
#include <hip/hip_runtime.h>

// BatchWiseSimCLR: out = mean_b,i logsumexp_{j!=i}(cos(z_bi,z_bj)/T) - mean_r cos(x_r,xp_r)/T
// 2B=128 batch rows, MS=512 items/batch, D=256, T=0.5.

#define TWO_B   128
#define MS      512
#define DDIM    256
#define NROWS   32768          // TWO_B * K = 128*256
#define TEMP_INV 2.0f
#define EPSN     1e-8f
#define SQRT2   1.41421356237f

typedef __attribute__((ext_vector_type(8))) short  short8;   // 8 x bf16 (4 VGPRs)
typedef __attribute__((ext_vector_type(4))) float  f32x4;    // MFMA acc

__device__ __forceinline__ unsigned short f2bf(float f) {
  union { float f; unsigned u; } c; c.f = f;
  unsigned r = (c.u + 0x7FFFu + ((c.u >> 16) & 1u)) >> 16;   // RNE
  return (unsigned short)r;
}

// global_load_lds, 16B per lane; lds dest = wave-uniform base (+lane*16 by HW)
#define GLDS16(gp, lp)                                                         \
  __builtin_amdgcn_global_load_lds(                                            \
      (const __attribute__((address_space(1))) unsigned int*)(gp),             \
      (__attribute__((address_space(3))) unsigned int*)(lp), 16, 0, 0)

// ================= FAST PATH (needs 32MB+4KB workspace) =================

// ---- K1f: row norms + write normalized bf16 zn (scaled by sqrt2) ----
// zn row (b*512+j): 256 ushorts, pre-swizzled in 16B granules:
// ushort u at offset u ^ ((j&7)<<3). sqrt2 fold: dot(zn_i,zn_j) = 2*cos = cos/T.
__global__ __launch_bounds__(256) void k_norm_f(
    const float* __restrict__ x, const float* __restrict__ xp,
    unsigned short* __restrict__ zn) {
  const int wid = threadIdx.x >> 6, lane = threadIdx.x & 63;
  #pragma unroll
  for (int itr = 0; itr < 4; ++itr) {
    const int r = itr * 8192 + blockIdx.x * 4 + wid;
    const int b = r & 127, i = r >> 7;          // r = i*128 + b
    const float4 a = ((const float4*)(x  + (size_t)r * DDIM))[lane];
    const float4 p = ((const float4*)(xp + (size_t)r * DDIM))[lane];
    float sxx = a.x*a.x + a.y*a.y + a.z*a.z + a.w*a.w;
    float spp = p.x*p.x + p.y*p.y + p.z*p.z + p.w*p.w;
    #pragma unroll
    for (int m = 1; m < 64; m <<= 1) {
      sxx += __shfl_xor(sxx, m);
      spp += __shfl_xor(spp, m);
    }
    const float inx = SQRT2 / fmaxf(sqrtf(sxx), EPSN);
    const float inp = SQRT2 / fmaxf(sqrtf(spp), EPSN);
    const int us = (lane * 4) ^ ((i & 7) << 3);
    ushort4 ox, op;
    ox.x = f2bf(a.x * inx); ox.y = f2bf(a.y * inx);
    ox.z = f2bf(a.z * inx); ox.w = f2bf(a.w * inx);
    op.x = f2bf(p.x * inp); op.y = f2bf(p.y * inp);
    op.z = f2bf(p.z * inp); op.w = f2bf(p.w * inp);
    *(ushort4*)(zn + ((size_t)(b * MS + i)       * DDIM) + us) = ox;
    *(ushort4*)(zn + ((size_t)(b * MS + 256 + i) * DDIM) + us) = op;
  }
}

// ---- K2f: gram + exp row-sums. A-frags in regs (wave owns 32 rows),
// B double-buffered via global_load_lds + counted vmcnt; epilogue of tile
// jt-1 pipelined into tile jt's MFMA phase (acc parity double-set).
__device__ __forceinline__ void stage_b(const unsigned short* g,
                                        unsigned short* d, int wid, int lane) {
  #pragma unroll
  for (int s = 0; s < 8; ++s) {
    const int c = wid * 8 + s;                  // 1 KB chunks
    GLDS16(g + c * 512 + lane * 8, d + c * 512);
  }
}

__global__ __launch_bounds__(256) void k_neg_f(
    const unsigned short* __restrict__ zn,
    float* __restrict__ negp, float* __restrict__ posn) {
  __shared__ __align__(16) unsigned short buf[2][64 * 256];   // 2 x 32 KB
  const int b  = blockIdx.x;      // linear id = it*128+b; 128%8==0 -> same-b same-XCD
  const int it = blockIdx.y;      // 0..3, 128-row A tile
  const int lane = threadIdx.x & 63, wid = threadIdx.x >> 6;

  // stage A (128 rows) into buf0 (rows 0-63) + buf1 (rows 64-127)
  {
    const unsigned short* gA = zn + (size_t)(b * MS + it * 128) * DDIM;
    #pragma unroll
    for (int s = 0; s < 8; ++s) {
      const int c = wid * 8 + s;
      GLDS16(gA + c * 512 + lane * 8, buf[0] + c * 512);
      GLDS16(gA + 32768 + c * 512 + lane * 8, buf[1] + c * 512);
    }
  }
  __syncthreads();                              // drains vmcnt: A complete

  // A-frags -> regs: wave owns A-rows wid*32..wid*32+31
  short8 av[2][8];
  {
    const unsigned short* src = buf[wid >> 1];
    #pragma unroll
    for (int rb = 0; rb < 2; ++rb) {
      const int ar = (wid & 1) * 32 + rb * 16 + (lane & 15);  // local row in buffer
      #pragma unroll
      for (int kk = 0; kk < 8; ++kk) {
        const int col = kk * 32 + ((lane >> 4) << 3);
        av[rb][kk] = *(const short8*)(src + ar * 256 + (col ^ ((ar & 7) << 3)));
      }
    }
  }
  __syncthreads();                              // all A reads done; bufs free

  // B pipeline: tile jt lives in buf[jt&1]; keep 2 tiles in flight
  const unsigned short* gB = zn + (size_t)b * MS * DDIM;
  stage_b(gB, buf[0], wid, lane);               // tile 0
  stage_b(gB + 32768, buf[1], wid, lane);       // tile 1

  float rowacc[2][4] = {{0,0,0,0},{0,0,0,0}};
  float posl = 0.0f;
  f32x4 acc[2][2][4];                           // [jt parity][rb][ni]

  const int ri = (lane >> 4) << 2;              // C/D row base within 16-tile
  const int ci = lane & 15;                     // C/D col within 16-tile
  const int tb0 = it * 128 + wid * 32;          // wave's first global A-row

  // epilogue of tile t (acc[t&1]): exp + row-sum; uniform-branch diag/pos tiles
  #define EPILOGUE(t)                                                          \
    {                                                                          \
      _Pragma("unroll")                                                        \
      for (int rb = 0; rb < 2; ++rb) {                                         \
        const int tb = tb0 + rb * 16;                                          \
        _Pragma("unroll")                                                      \
        for (int ni = 0; ni < 4; ++ni) {                                       \
          const int jtb = (t) * 64 + ni * 16;                                  \
          const bool dtile = (jtb == tb);        /* wave-uniform */            \
          const bool ptile = (jtb == tb + 256);  /* wave-uniform */            \
          _Pragma("unroll")                                                    \
          for (int r2 = 0; r2 < 4; ++r2) {                                     \
            const float s = acc[(t) & 1][rb][ni][r2];                          \
            float e = __expf(s);                                               \
            if (dtile && ci == ri + r2) e = 0.0f;                              \
            rowacc[rb][r2] += e;                                               \
            if (ptile && ci == ri + r2) posl += s;                             \
          }                                                                    \
        }                                                                      \
      }                                                                        \
    }

  #pragma unroll
  for (int jt = 0; jt < 8; ++jt) {
    // wait: tile jt's chunks done (tile jt+1's 8 may stay in flight)
    if (jt == 7) asm volatile("s_waitcnt vmcnt(0)" ::: "memory");
    else         asm volatile("s_waitcnt vmcnt(8)" ::: "memory");
    __builtin_amdgcn_sched_barrier(0);
    __builtin_amdgcn_s_barrier();               // tile jt fully in LDS
    __builtin_amdgcn_sched_barrier(0);

    const unsigned short* Bsrc = buf[jt & 1];
    #pragma unroll
    for (int rb = 0; rb < 2; ++rb)
      #pragma unroll
      for (int ni = 0; ni < 4; ++ni)
        acc[jt & 1][rb][ni] = (f32x4){0, 0, 0, 0};

    // pipelined epilogue of previous tile: interleaves (trans/VALU) with MFMAs
    if (jt >= 1) EPILOGUE(jt - 1);

    __builtin_amdgcn_s_setprio(1);
    #pragma unroll
    for (int kk = 0; kk < 8; ++kk) {
      const int col = kk * 32 + ((lane >> 4) << 3);
      #pragma unroll
      for (int ni = 0; ni < 4; ++ni) {
        const int br = ni * 16 + (lane & 15);
        const short8 bv = *(const short8*)(Bsrc + br * 256 + (col ^ ((br & 7) << 3)));
        acc[jt & 1][0][ni] = __builtin_amdgcn_mfma_f32_16x16x32_bf16(av[0][kk], bv, acc[jt & 1][0][ni], 0, 0, 0);
        acc[jt & 1][1][ni] = __builtin_amdgcn_mfma_f32_16x16x32_bf16(av[1][kk], bv, acc[jt & 1][1][ni], 0, 0, 0);
      }
    }
    __builtin_amdgcn_s_setprio(0);

    __builtin_amdgcn_sched_barrier(0);
    __builtin_amdgcn_s_barrier();               // all reads of buf[jt&1] done
    __builtin_amdgcn_sched_barrier(0);
    if (jt < 6) stage_b(gB + (size_t)(jt + 2) * 32768, buf[jt & 1], wid, lane);
  }
  EPILOGUE(7);
  #undef EPILOGUE

  // full row sums within each 16-lane group, then log
  float partial = 0.0f;
  #pragma unroll
  for (int rb = 0; rb < 2; ++rb)
    #pragma unroll
    for (int r2 = 0; r2 < 4; ++r2) {
      float v = rowacc[rb][r2];
      v += __shfl_xor(v, 1); v += __shfl_xor(v, 2);
      v += __shfl_xor(v, 4); v += __shfl_xor(v, 8);
      partial += __logf(v);
    }
  // one representative per 16-lane group -> wave total in every lane
  partial += __shfl_xor(partial, 16);
  partial += __shfl_xor(partial, 32);
  // posl: distinct contributions per lane -> full butterfly
  #pragma unroll
  for (int m = 1; m < 64; m <<= 1) posl += __shfl_xor(posl, m);

  __shared__ float sn[4], sp2[4];
  if (lane == 0) { sn[wid] = partial; sp2[wid] = posl; }
  __syncthreads();
  if (threadIdx.x == 0) {
    const int bid = blockIdx.y * TWO_B + blockIdx.x;
    negp[bid] = sn[0] + sn[1] + sn[2] + sn[3];
    posn[bid] = sp2[0] + sp2[1] + sp2[2] + sp2[3];
  }
}

// ---- K3f: reduce the two 512-entry partial arrays ----
__global__ __launch_bounds__(256) void k_fin_f(
    const float* __restrict__ posn, const float* __restrict__ negp,
    float* __restrict__ out) {
  const int t = threadIdx.x, wid = t >> 6, lane = t & 63;
  float p = posn[t] + posn[t + 256];
  float n = negp[t] + negp[t + 256];
  #pragma unroll
  for (int m = 1; m < 64; m <<= 1) { p += __shfl_xor(p, m); n += __shfl_xor(n, m); }
  __shared__ float sp[4], sq[4];
  if (lane == 0) { sp[wid] = p; sq[wid] = n; }
  __syncthreads();
  if (t == 0) {
    const float pt = sp[0] + sp[1] + sp[2] + sp[3];
    const float nt = sq[0] + sq[1] + sq[2] + sq[3];
    out[0] = nt * (1.0f / 65536.0f) - pt * (1.0f / 32768.0f);
  }
}

// ================= FALLBACK PATH (R5, small workspace, verified) =================

__global__ __launch_bounds__(256) void k_norm(
    const float* __restrict__ x, const float* __restrict__ xp,
    float* __restrict__ invx, float* __restrict__ invp, float* __restrict__ posp) {
  const int wid = threadIdx.x >> 6, lane = threadIdx.x & 63;
  float posl = 0.0f;
  #pragma unroll
  for (int itr = 0; itr < 8; ++itr) {
    const int r = itr * 4096 + blockIdx.x * 4 + wid;
    const float4 a = ((const float4*)(x  + (size_t)r * DDIM))[lane];
    const float4 b = ((const float4*)(xp + (size_t)r * DDIM))[lane];
    float sxx = a.x*a.x + a.y*a.y + a.z*a.z + a.w*a.w;
    float spp = b.x*b.x + b.y*b.y + b.z*b.z + b.w*b.w;
    float sxp = a.x*b.x + a.y*b.y + a.z*b.z + a.w*b.w;
    #pragma unroll
    for (int m = 1; m < 64; m <<= 1) {
      sxx += __shfl_xor(sxx, m);
      spp += __shfl_xor(spp, m);
      sxp += __shfl_xor(sxp, m);
    }
    const float inx = 1.0f / fmaxf(sqrtf(sxx), EPSN);
    const float inp = 1.0f / fmaxf(sqrtf(spp), EPSN);
    if (lane == 0) {
      invx[r] = inx; invp[r] = inp;
      posl += sxp * inx * inp * TEMP_INV;
    }
  }
  __shared__ float cp[4];
  if (lane == 0) cp[wid] = posl;
  __syncthreads();
  if (threadIdx.x == 0) posp[blockIdx.x] = cp[0] + cp[1] + cp[2] + cp[3];
}

__device__ __forceinline__ void stage_tile(
    unsigned short* dst, const float* __restrict__ x, const float* __restrict__ xp,
    const float* __restrict__ invx, const float* __restrict__ invp, int b, int tilebase) {
  const int t = threadIdx.x;
  const bool isp = (tilebase >= 256);
  const float* src = isp ? xp : x;
  const float* inv = isp ? invp : invx;
  const int base_i = isp ? (tilebase - 256) : tilebase;
  #pragma unroll
  for (int s = 0; s < 16; ++s) {
    const int u   = s * 256 + t;
    const int row = u >> 6, c4 = u & 63;
    const int g   = (base_i + row) * TWO_B + b;
    const float4 v = *(const float4*)(src + (size_t)g * DDIM + c4 * 4);
    const float sc = inv[g];
    ushort4 o;
    o.x = f2bf(v.x * sc); o.y = f2bf(v.y * sc);
    o.z = f2bf(v.z * sc); o.w = f2bf(v.w * sc);
    *(ushort4*)(dst + row * 256 + ((c4 * 4) ^ ((row & 7) << 3))) = o;
  }
}

__global__ __launch_bounds__(256, 2) void k_neg(
    const float* __restrict__ x, const float* __restrict__ xp,
    const float* __restrict__ invx, const float* __restrict__ invp,
    float* __restrict__ negp) {
  __shared__ __align__(16) unsigned short As[64 * 256];
  __shared__ __align__(16) unsigned short Bs[64 * 256];
  const int b  = blockIdx.x;
  const int it = blockIdx.y;
  const int lane = threadIdx.x & 63, wid = threadIdx.x >> 6;

  stage_tile(As, x, xp, invx, invp, b, it * 64);
  float rowacc[4] = {0, 0, 0, 0};

  for (int jt = 0; jt < 8; ++jt) {
    __syncthreads();
    stage_tile(Bs, x, xp, invx, invp, b, jt * 64);
    __syncthreads();

    f32x4 acc[4] = {{0,0,0,0},{0,0,0,0},{0,0,0,0},{0,0,0,0}};
    #pragma unroll
    for (int kk = 0; kk < 8; ++kk) {
      const int col = kk * 32 + ((lane >> 4) << 3);
      const int ar  = wid * 16 + (lane & 15);
      const short8 av = *(const short8*)(As + ar * 256 + (col ^ ((ar & 7) << 3)));
      #pragma unroll
      for (int ni = 0; ni < 4; ++ni) {
        const int br = ni * 16 + (lane & 15);
        const short8 bv = *(const short8*)(Bs + br * 256 + (col ^ ((br & 7) << 3)));
        acc[ni] = __builtin_amdgcn_mfma_f32_16x16x32_bf16(av, bv, acc[ni], 0, 0, 0);
      }
    }
    const int igb = it * 64 + wid * 16 + ((lane >> 4) << 2);
    #pragma unroll
    for (int ni = 0; ni < 4; ++ni) {
      const int jg = jt * 64 + ni * 16 + (lane & 15);
      #pragma unroll
      for (int r2 = 0; r2 < 4; ++r2) {
        const float s = acc[ni][r2] * TEMP_INV;
        rowacc[r2] += ((igb + r2) == jg) ? 0.0f : __expf(s);
      }
    }
  }

  float partial = 0.0f;
  #pragma unroll
  for (int r2 = 0; r2 < 4; ++r2) {
    float v = rowacc[r2];
    v += __shfl_xor(v, 1); v += __shfl_xor(v, 2);
    v += __shfl_xor(v, 4); v += __shfl_xor(v, 8);
    partial += __logf(v);
  }
  partial += __shfl_xor(partial, 16);
  partial += __shfl_xor(partial, 32);

  __shared__ float sn[4];
  if (lane == 0) sn[wid] = partial;
  __syncthreads();
  if (threadIdx.x == 0)
    negp[blockIdx.y * TWO_B + blockIdx.x] = sn[0] + sn[1] + sn[2] + sn[3];
}

__global__ __launch_bounds__(256) void k_fin(
    const float* __restrict__ posp, const float* __restrict__ negp,
    float* __restrict__ out) {
  const int t = threadIdx.x, wid = t >> 6, lane = t & 63;
  const float4 p4 = ((const float4*)posp)[t];
  const float4 n4 = ((const float4*)negp)[t];
  float p = p4.x + p4.y + p4.z + p4.w;
  float n = n4.x + n4.y + n4.z + n4.w;
  #pragma unroll
  for (int m = 1; m < 64; m <<= 1) { p += __shfl_xor(p, m); n += __shfl_xor(n, m); }
  __shared__ float sp[4], sq[4];
  if (lane == 0) { sp[wid] = p; sq[wid] = n; }
  __syncthreads();
  if (t == 0) {
    const float pt = sp[0] + sp[1] + sp[2] + sp[3];
    const float nt = sq[0] + sq[1] + sq[2] + sq[3];
    out[0] = nt * (1.0f / 65536.0f) - pt * (1.0f / 32768.0f);
  }
}

extern "C" void kernel_launch(void* const* d_in, const int* in_sizes, int n_in,
                              void* d_out, int out_size, void* d_ws, size_t ws_size,
                              hipStream_t stream) {
  const float* x  = (const float*)d_in[0];
  const float* xp = (const float*)d_in[1];
  float* wsf = (float*)d_ws;
  float* out = (float*)d_out;

  const size_t need_fast = 4096 + (size_t)65536 * DDIM * 2;   // partials + 32MB zn
  if (ws_size >= need_fast) {
    float* negp = wsf;                        // 512
    float* posn = wsf + 512;                  // 512
    unsigned short* zn = (unsigned short*)(wsf + 1024);
    k_norm_f<<<2048, 256, 0, stream>>>(x, xp, zn);
    k_neg_f<<<dim3(TWO_B, 4), 256, 0, stream>>>(zn, negp, posn);
    k_fin_f<<<1, 256, 0, stream>>>(posn, negp, out);
  } else {
    float* invx = wsf;
    float* invp = wsf + NROWS;
    float* posp = wsf + 2 * NROWS;
    float* negp = wsf + 2 * NROWS + 1024;
    k_norm<<<1024, 256, 0, stream>>>(x, xp, invx, invp, posp);
    k_neg<<<dim3(TWO_B, 8), 256, 0, stream>>>(x, xp, invx, invp, negp);
    k_fin<<<1, 256, 0, stream>>>(posp, negp, out);
  }
}